// Round 4
// baseline (840.381 us; speedup 1.0000x reference)
//
#include <hip/hip_runtime.h>
#include <hip/hip_bf16.h>
#include <stdint.h>

#define NB 8192
#define DD 1024
#define HRD 512
#define HED 4096
#define HFD 2048
#define KR3 3072   // router concatenated K = 3*DD

typedef __attribute__((ext_vector_type(8))) short bf16x8;
typedef __attribute__((ext_vector_type(4))) float f32x4;
typedef unsigned short u16;

__device__ __forceinline__ u16 f2b(float f) {
    union { float f; uint32_t i; } c; c.f = f;
    uint32_t r = c.i + 0x7FFF + ((c.i >> 16) & 1);   // RNE
    return (u16)(r >> 16);
}
__device__ __forceinline__ float b2f(u16 u) {
    union { uint32_t i; float f; } c; c.i = ((uint32_t)u) << 16; return c.f;
}
__device__ __forceinline__ void glds16(const char* g, char* l) {
    __builtin_amdgcn_global_load_lds((const __attribute__((address_space(1))) void*)g,
                                     (__attribute__((address_space(3))) void*)l, 16, 0, 0);
}

// ---------------- init ----------------
__global__ void k_init(int* cnt) { if (threadIdx.x < 2) cnt[threadIdx.x] = 0; }

// ---------------- split x into router A'' = [xh | xh | xl], rows of 3072 bf16 ----------------
__global__ __launch_bounds__(256) void k_split3(const float4* __restrict__ x4,
                                                ushort4* __restrict__ a3) {
    int i4 = blockIdx.x * 256 + threadIdx.x;     // over NB*DD/4
    int row = i4 >> 8, c4 = i4 & 255;            // 256 float4 per row
    float4 v = x4[i4];
    ushort4 h, l;
    h.x = f2b(v.x); l.x = f2b(v.x - b2f(h.x));
    h.y = f2b(v.y); l.y = f2b(v.y - b2f(h.y));
    h.z = f2b(v.z); l.z = f2b(v.z - b2f(h.z));
    h.w = f2b(v.w); l.w = f2b(v.w - b2f(h.w));
    ushort4* ob = a3 + (size_t)row * 768;        // 3072/4
    ob[c4] = h; ob[c4 + 256] = h; ob[c4 + 512] = l;
}

// ---------------- transpose fp32 [R][C] -> bf16 [C][R] ----------------
__global__ __launch_bounds__(256) void k_transpose(const float* __restrict__ in,
                                                   u16* __restrict__ out, int R, int C) {
    __shared__ float s[64][65];
    int tx = threadIdx.x & 63, ty = threadIdx.x >> 6;
    int c0 = blockIdx.x * 64, r0 = blockIdx.y * 64;
#pragma unroll
    for (int j = 0; j < 16; j++) { int r = ty + j * 4; s[r][tx] = in[(size_t)(r0 + r) * C + c0 + tx]; }
    __syncthreads();
#pragma unroll
    for (int j = 0; j < 16; j++) { int c = ty + j * 4; out[(size_t)(c0 + c) * R + r0 + tx] = f2b(s[tx][c]); }
}

// ---------------- transpose W_r1 [1024][512] -> B'' rows [Wh | Wl | Wh], 512 x 3072 ----------------
__global__ __launch_bounds__(256) void k_transpose3(const float* __restrict__ in,
                                                    u16* __restrict__ out, int R, int C) {
    __shared__ float s[64][65];
    int tx = threadIdx.x & 63, ty = threadIdx.x >> 6;
    int c0 = blockIdx.x * 64, r0 = blockIdx.y * 64;
#pragma unroll
    for (int j = 0; j < 16; j++) { int r = ty + j * 4; s[r][tx] = in[(size_t)(r0 + r) * C + c0 + tx]; }
    __syncthreads();
#pragma unroll
    for (int j = 0; j < 16; j++) {
        int c = ty + j * 4;
        float v = s[tx][c];
        u16 h = f2b(v);
        u16 l = f2b(v - b2f(h));
        u16* ob = out + (size_t)(c0 + c) * KR3 + r0 + tx;
        ob[0] = h; ob[DD] = l; ob[2 * DD] = h;
    }
}

// ---------------- router heads: fp32 dots, argmaxes, softmax weight, compaction ----------------
__global__ __launch_bounds__(256) void k_heads(const float* __restrict__ H,
                                               const float* __restrict__ Wd, const float* __restrict__ bd,
                                               const float* __restrict__ Wm, const float* __restrict__ Wl,
                                               int* __restrict__ cnt, int* __restrict__ perm,
                                               float* __restrict__ wsc, int* __restrict__ eic) {
    int lane = threadIdx.x & 63, wave = threadIdx.x >> 6;
    int r = blockIdx.x * 4 + wave;
    const float4* h4 = (const float4*)(H + (size_t)r * HRD);
    float4 v0 = h4[lane * 2], v1 = h4[lane * 2 + 1];
    float hv[8] = {v0.x, v0.y, v0.z, v0.w, v1.x, v1.y, v1.z, v1.w};
    float a[10];
#pragma unroll
    for (int t = 0; t < 10; t++) a[t] = 0.f;
    int kbase = lane * 8;
#pragma unroll
    for (int j = 0; j < 8; j++) {
        int k = kbase + j;
        float h_ = hv[j];
        float2 wd = ((const float2*)Wd)[k];
        a[0] += h_ * wd.x; a[1] += h_ * wd.y;
        float4 wm = ((const float4*)Wm)[k];
        a[2] += h_ * wm.x; a[3] += h_ * wm.y; a[4] += h_ * wm.z; a[5] += h_ * wm.w;
        float4 wl = ((const float4*)Wl)[k];
        a[6] += h_ * wl.x; a[7] += h_ * wl.y; a[8] += h_ * wl.z; a[9] += h_ * wl.w;
    }
#pragma unroll
    for (int t = 0; t < 10; t++)
#pragma unroll
        for (int off = 32; off > 0; off >>= 1) a[t] += __shfl_down(a[t], off);
    if (lane == 0) {
        float d0 = a[0] + bd[0], d1 = a[1] + bd[1];
        int primary = (d1 > d0) ? 1 : 0;                       // first-max tie-break
        float w = 1.f / (1.f + expf(-fabsf(d0 - d1)));         // softmax weight of chosen
        int mi = 0; float mv = a[2];
        if (a[3] > mv) { mv = a[3]; mi = 1; }
        if (a[4] > mv) { mv = a[4]; mi = 2; }
        if (a[5] > mv) { mv = a[5]; mi = 3; }
        int li = 0; float lv = a[6];
        if (a[7] > lv) { lv = a[7]; li = 1; }
        if (a[8] > lv) { lv = a[8]; li = 2; }
        if (a[9] > lv) { lv = a[9]; li = 3; }
        int pos;
        if (primary == 0) pos = atomicAdd(&cnt[0], 1);
        else              pos = NB - 1 - atomicAdd(&cnt[1], 1);
        perm[pos] = r; wsc[pos] = w; eic[pos] = (primary == 0) ? mi : li;
    }
}

// ---------------- gather: xin_c[i] = bf16(x[perm[i]] + emb[eic[i]]) ----------------
__global__ __launch_bounds__(256) void k_gather(const float* __restrict__ x,
                                                const float* __restrict__ op_emb,
                                                const float* __restrict__ task_emb,
                                                const int* __restrict__ perm, const int* __restrict__ eic,
                                                const int* __restrict__ cnt, u16* __restrict__ xin) {
    int lane = threadIdx.x & 63, wave = threadIdx.x >> 6;
    int i = blockIdx.x * 4 + wave;
    int n0 = cnt[0];
    int r = perm[i];
    const float* emb = ((i >= n0) ? task_emb : op_emb) + (size_t)eic[i] * DD;
    const float4* x4 = (const float4*)(x + (size_t)r * DD);
    const float4* e4 = (const float4*)emb;
    ushort4* o4 = (ushort4*)(xin + (size_t)i * DD);
#pragma unroll
    for (int j = 0; j < 4; j++) {
        int idx = lane + j * 64;
        float4 xv = x4[idx], ev = e4[idx];
        ushort4 o;
        o.x = f2b(xv.x + ev.x); o.y = f2b(xv.y + ev.y);
        o.z = f2b(xv.z + ev.z); o.w = f2b(xv.w + ev.w);
        o4[idx] = o;
    }
}

// ---------------- stage one 128x64 bf16 tile into LDS via global_load_lds ----------------
__device__ __forceinline__ void stage_tile(const char* gBase, long rowStrideBytes,
                                           u16* s, int tid) {
    int wave = tid >> 6, lane = tid & 63;
#pragma unroll
    for (int is = 0; is < 4; ++is) {
        int c = wave * 4 + is;                 // 1KB chunk, wave-uniform
        long go = (long)(c * 8 + (lane >> 3)) * rowStrideBytes + (lane & 7) * 16;
        glds16(gBase + go, (char*)s + c * 1024);
    }
}

// ---------------- unified double-buffered 128x128 GEMM: A[M][K] @ Bt[N][K]^T ----------------
// dbuf K-loop: stage tile k+1 BEFORE computing tile k; single barrier per k0 (its implicit
// vmcnt(0) drain lands AFTER compute, so load latency hides under MFMA). 64KB LDS = 2 blocks/CU,
// which matches what the small grids can supply anyway.
// DUAL: grid.y = 65 row-tiles: t<=tb -> math on tile t, else lang on tile t-1; boundary
//       tile double-computed, stores row-masked.
// EPI 0: relu -> bf16; EPI 1: *wsel -> bf16; EPI 2: + resid, scatter fp32 via perm; EPI 3: relu -> fp32.
template <int EPI, bool DUAL>
__global__ __launch_bounds__(256) void k_gemm_db(const u16* __restrict__ A,
                                                 const u16* __restrict__ Btm, const u16* __restrict__ Btl,
                                                 const float* __restrict__ biasm, const float* __restrict__ biasl,
                                                 void* __restrict__ Out, int K, int N,
                                                 const int* __restrict__ cnt, const float* __restrict__ wsel,
                                                 const int* __restrict__ perm, const u16* __restrict__ resid) {
    __shared__ u16 sA[2][128 * 64];
    __shared__ u16 sB[2][128 * 64];
    int tid = threadIdx.x, lane = tid & 63, wave = tid >> 6;
    int bn = blockIdx.x, t = blockIdx.y;
    int tile = t, storeLo, storeHi;
    const u16* Bt = Btm; const float* bias = biasm;
    if constexpr (DUAL) {
        int n0 = cnt[0];
        int tb = n0 >> 7;
        bool isMath = (t <= tb) && (t < NB / 128);
        tile = isMath ? t : t - 1;
        int lo = tile * 128, hi = lo + 128;
        if (isMath) { storeLo = lo; storeHi = n0 < hi ? n0 : hi; }
        else        { storeLo = n0 > lo ? n0 : lo; storeHi = hi; }
        if (storeLo >= storeHi) return;   // block-uniform
        if (!isMath) { Bt = Btl; bias = biasl; }
    } else {
        storeLo = t * 128; storeHi = storeLo + 128;
    }
    f32x4 acc[4][4];
#pragma unroll
    for (int i = 0; i < 4; i++)
#pragma unroll
        for (int j = 0; j < 4; j++) acc[i][j] = (f32x4)0.f;
    int wm = (wave & 1) * 64, wn = (wave >> 1) * 64;
    const long ks = (long)K * 2;
    const char* aBase = (const char*)A + (size_t)tile * 128 * ks;
    const char* bBase = (const char*)Bt + (size_t)bn * 128 * ks;

    stage_tile(aBase, ks, sA[0], tid);
    stage_tile(bBase, ks, sB[0], tid);
    __syncthreads();
    int cur = 0;
    for (int k0 = 64; ; k0 += 64) {
        bool more = (k0 < K);
        if (more) {
            stage_tile(aBase + (long)k0 * 2, ks, sA[cur ^ 1], tid);
            stage_tile(bBase + (long)k0 * 2, ks, sB[cur ^ 1], tid);
        }
        const u16* cA = sA[cur];
        const u16* cB = sB[cur];
#pragma unroll
        for (int kk = 0; kk < 2; kk++) {
            int kofs = kk * 64 + (lane >> 4) * 16;
            bf16x8 vb[4];
#pragma unroll
            for (int ni = 0; ni < 4; ni++)
                vb[ni] = *(const bf16x8*)((const char*)cB + (wn + ni * 16 + (lane & 15)) * 128 + kofs);
#pragma unroll
            for (int mi = 0; mi < 4; mi++) {
                bf16x8 va = *(const bf16x8*)((const char*)cA + (wm + mi * 16 + (lane & 15)) * 128 + kofs);
#pragma unroll
                for (int ni = 0; ni < 4; ni++)
                    acc[mi][ni] = __builtin_amdgcn_mfma_f32_16x16x32_bf16(va, vb[ni], acc[mi][ni], 0, 0, 0);
            }
        }
        if (!more) break;
        __syncthreads();   // drains vmcnt(0) for next tile's loads — AFTER compute
        cur ^= 1;
    }
    int quad = lane >> 4, cl = lane & 15;
#pragma unroll
    for (int mi = 0; mi < 4; mi++)
#pragma unroll
        for (int r = 0; r < 4; r++) {
            int grow = tile * 128 + wm + mi * 16 + quad * 4 + r;
            if (grow < storeLo || grow >= storeHi) continue;
            float wrow = 0.f;
            if constexpr (EPI == 1) wrow = wsel[grow];
#pragma unroll
            for (int ni = 0; ni < 4; ni++) {
                int col = bn * 128 + wn + ni * 16 + cl;
                float v = acc[mi][ni][r] + bias[col];
                if constexpr (EPI == 0) {
                    ((u16*)Out)[(size_t)grow * N + col] = f2b(fmaxf(v, 0.f));
                } else if constexpr (EPI == 1) {
                    ((u16*)Out)[(size_t)grow * N + col] = f2b(v * wrow);
                } else if constexpr (EPI == 2) {
                    v += b2f(resid[(size_t)grow * N + col]);
                    ((float*)Out)[(size_t)perm[grow] * N + col] = v;
                } else {
                    ((float*)Out)[(size_t)grow * N + col] = fmaxf(v, 0.f);
                }
            }
        }
}

extern "C" void kernel_launch(void* const* d_in, const int* in_sizes, int n_in,
                              void* d_out, int out_size, void* d_ws, size_t ws_size,
                              hipStream_t stream) {
    const float* x      = (const float*)d_in[0];
    const float* W_r1   = (const float*)d_in[1];
    const float* b_r1   = (const float*)d_in[2];
    const float* W_dom  = (const float*)d_in[3];
    const float* b_dom  = (const float*)d_in[4];
    const float* W_mop  = (const float*)d_in[5];
    const float* W_lt   = (const float*)d_in[6];
    const float* op_emb = (const float*)d_in[7];
    const float* W_m1   = (const float*)d_in[8];
    const float* b_m1   = (const float*)d_in[9];
    const float* W_m2   = (const float*)d_in[10];
    const float* b_m2   = (const float*)d_in[11];
    const float* task_emb = (const float*)d_in[12];
    const float* W_l1   = (const float*)d_in[13];
    const float* b_l1   = (const float*)d_in[14];
    const float* W_l2   = (const float*)d_in[15];
    const float* b_l2   = (const float*)d_in[16];
    const float* W_f1   = (const float*)d_in[17];
    const float* b_f1   = (const float*)d_in[18];
    const float* W_f2   = (const float*)d_in[19];
    const float* b_f2   = (const float*)d_in[20];

    char* wsp = (char*)d_ws;
    size_t off = 0;
    auto take = [&](size_t bytes) -> char* {
        char* p = wsp + off;
        off += (bytes + 255) & ~(size_t)255;
        return p;
    };
    u16* Brt   = (u16*)take((size_t)HRD * KR3 * 2);  // router B'' 512x3072
    u16* Wm1t  = (u16*)take((size_t)HED * DD * 2);
    u16* Wl1t  = (u16*)take((size_t)HED * DD * 2);
    u16* Wm2t  = (u16*)take((size_t)DD * HED * 2);
    u16* Wl2t  = (u16*)take((size_t)DD * HED * 2);
    u16* Wf1t  = (u16*)take((size_t)HFD * DD * 2);
    u16* Wf2t  = (u16*)take((size_t)DD * HFD * 2);
    u16* hid   = (u16*)take((size_t)NB * HED * 2);   // 64 MB
    float* Hbuf = (float*)take((size_t)NB * HRD * 4);
    u16* xin   = (u16*)take((size_t)NB * DD * 2);
    u16* fused = (u16*)take((size_t)NB * DD * 2);
    int* cnt   = (int*)take(256);
    int* perm  = (int*)take(NB * 4);
    int* eic   = (int*)take(NB * 4);
    float* wsc = (float*)take(NB * 4);
    // aliases (lifetime-disjoint):
    u16* Abig  = hid;    // router A'' 8192x3072 (48MB) lives in hid (64MB); consumed before L1 writes hid
    u16* hid2  = Wm1t;   // F1 output (32MB) over Wm1t..Wl2t (consumed by L1/L2)

    k_init<<<1, 64, 0, stream>>>(cnt);
    k_split3<<<(NB * DD / 4) / 256, 256, 0, stream>>>((const float4*)x, (ushort4*)Abig);
    k_transpose3<<<dim3(HRD / 64, DD / 64), 256, 0, stream>>>(W_r1, Brt, DD, HRD);
    k_transpose<<<dim3(HED / 64, DD / 64), 256, 0, stream>>>(W_m1, Wm1t, DD, HED);
    k_transpose<<<dim3(HED / 64, DD / 64), 256, 0, stream>>>(W_l1, Wl1t, DD, HED);
    k_transpose<<<dim3(DD / 64, HED / 64), 256, 0, stream>>>(W_m2, Wm2t, HED, DD);
    k_transpose<<<dim3(DD / 64, HED / 64), 256, 0, stream>>>(W_l2, Wl2t, HED, DD);
    k_transpose<<<dim3(HFD / 64, DD / 64), 256, 0, stream>>>(W_f1, Wf1t, DD, HFD);
    k_transpose<<<dim3(DD / 64, HFD / 64), 256, 0, stream>>>(W_f2, Wf2t, HFD, DD);

    // router GEMM: relu(A''@B''^T + b) -> Hbuf (fp32), K'=3072 gives exact hi/lo 3-term sum
    k_gemm_db<3, false><<<dim3(HRD / 128, NB / 128), 256, 0, stream>>>(
        Abig, Brt, nullptr, b_r1, nullptr, Hbuf, KR3, HRD, nullptr, nullptr, nullptr, nullptr);
    k_heads<<<NB / 4, 256, 0, stream>>>(Hbuf, W_dom, b_dom, W_mop, W_lt, cnt, perm, wsc, eic);
    k_gather<<<NB / 4, 256, 0, stream>>>(x, op_emb, task_emb, perm, eic, cnt, xin);

    // expert layer 1 fused (relu -> hid)
    k_gemm_db<0, true><<<dim3(HED / 128, NB / 128 + 1), 256, 0, stream>>>(
        xin, Wm1t, Wl1t, b_m1, b_l1, hid, DD, HED, cnt, nullptr, nullptr, nullptr);
    // expert layer 2 fused (scale by routing weight -> fused)
    k_gemm_db<1, true><<<dim3(DD / 128, NB / 128 + 1), 256, 0, stream>>>(
        hid, Wm2t, Wl2t, b_m2, b_l2, fused, HED, DD, cnt, wsc, nullptr, nullptr);
    // fusion MLP
    k_gemm_db<0, false><<<dim3(HFD / 128, NB / 128), 256, 0, stream>>>(
        fused, Wf1t, nullptr, b_f1, nullptr, hid2, DD, HFD, nullptr, nullptr, nullptr, nullptr);
    k_gemm_db<2, false><<<dim3(DD / 128, NB / 128), 256, 0, stream>>>(
        hid2, Wf2t, nullptr, b_f2, nullptr, d_out, HFD, DD, nullptr, nullptr, perm, fused);
}

// Round 5
// 773.205 us; speedup vs baseline: 1.0869x; 1.0869x over previous
//
#include <hip/hip_runtime.h>
#include <hip/hip_bf16.h>
#include <stdint.h>

#define NB 8192
#define DD 1024
#define HRD 512
#define HED 4096
#define HFD 2048

typedef __attribute__((ext_vector_type(8))) short bf16x8;
typedef __attribute__((ext_vector_type(4))) float f32x4;
typedef unsigned short u16;

__device__ __forceinline__ u16 f2b(float f) {
    union { float f; uint32_t i; } c; c.f = f;
    uint32_t r = c.i + 0x7FFF + ((c.i >> 16) & 1);   // RNE
    return (u16)(r >> 16);
}
__device__ __forceinline__ float b2f(u16 u) {
    union { uint32_t i; float f; } c; c.i = ((uint32_t)u) << 16; return c.f;
}
__device__ __forceinline__ void glds16(const char* g, char* l) {
    __builtin_amdgcn_global_load_lds((const __attribute__((address_space(1))) void*)g,
                                     (__attribute__((address_space(3))) void*)l, 16, 0, 0);
}

// ---------------- init ----------------
__global__ void k_init(int* cnt) { if (threadIdx.x < 2) cnt[threadIdx.x] = 0; }

// ---------------- split x into bf16 hi/lo ----------------
__global__ __launch_bounds__(256) void k_split(const float4* __restrict__ x4,
                                               ushort4* __restrict__ hi4,
                                               ushort4* __restrict__ lo4) {
    int i = blockIdx.x * 256 + threadIdx.x;
    float4 v = x4[i];
    ushort4 h, l;
    h.x = f2b(v.x); l.x = f2b(v.x - b2f(h.x));
    h.y = f2b(v.y); l.y = f2b(v.y - b2f(h.y));
    h.z = f2b(v.z); l.z = f2b(v.z - b2f(h.z));
    h.w = f2b(v.w); l.w = f2b(v.w - b2f(h.w));
    hi4[i] = h; lo4[i] = l;
}

// ---------------- transpose fp32 [R][C] -> bf16 [C][R] ----------------
__global__ __launch_bounds__(256) void k_transpose(const float* __restrict__ in,
                                                   u16* __restrict__ out, int R, int C) {
    __shared__ float s[64][65];
    int tx = threadIdx.x & 63, ty = threadIdx.x >> 6;
    int c0 = blockIdx.x * 64, r0 = blockIdx.y * 64;
#pragma unroll
    for (int j = 0; j < 16; j++) { int r = ty + j * 4; s[r][tx] = in[(size_t)(r0 + r) * C + c0 + tx]; }
    __syncthreads();
#pragma unroll
    for (int j = 0; j < 16; j++) { int c = ty + j * 4; out[(size_t)(c0 + c) * R + r0 + tx] = f2b(s[tx][c]); }
}

__global__ __launch_bounds__(256) void k_transpose_split(const float* __restrict__ in,
                                                         u16* __restrict__ ohi, u16* __restrict__ olo,
                                                         int R, int C) {
    __shared__ float s[64][65];
    int tx = threadIdx.x & 63, ty = threadIdx.x >> 6;
    int c0 = blockIdx.x * 64, r0 = blockIdx.y * 64;
#pragma unroll
    for (int j = 0; j < 16; j++) { int r = ty + j * 4; s[r][tx] = in[(size_t)(r0 + r) * C + c0 + tx]; }
    __syncthreads();
#pragma unroll
    for (int j = 0; j < 16; j++) {
        int c = ty + j * 4;
        float v = s[tx][c];
        u16 h = f2b(v);
        ohi[(size_t)(c0 + c) * R + r0 + tx] = h;
        olo[(size_t)(c0 + c) * R + r0 + tx] = f2b(v - b2f(h));
    }
}

// ---------------- stage one 128x64 bf16 tile into LDS via global_load_lds ----------------
__device__ __forceinline__ void stage_tile(const char* gBase, long rowStrideBytes,
                                           u16* s, int tid) {
    int wave = tid >> 6, lane = tid & 63;
#pragma unroll
    for (int is = 0; is < 4; ++is) {
        int c = wave * 4 + is;                 // 1KB chunk, wave-uniform
        long go = (long)(c * 8 + (lane >> 3)) * rowStrideBytes + (lane & 7) * 16;
        glds16(gBase + go, (char*)s + c * 1024);
    }
}

// ---------------- unified split-K 128x128 GEMM: A[M][Ktot] @ Bt[N][Ktot]^T ----------------
// Single-buffered m97 inner loop (measured best). blockIdx.z = K-chunk of length Kc.
// R3: router 3-term hi/lo split-K — chunk selects (Ah,Bh)/(Ah,Bl)/(Al,Bh), k-offset 0.
// DUAL: grid.y = 65 row-tiles: t<=tb -> math weights on tile t, else lang on tile t-1;
//       boundary tile double-computed, stores row-masked.
// EPI 0: relu -> bf16 direct (bias);  EPI 4: fp32 partial store (no bias) at chunk kc.
template <int EPI, bool DUAL, bool R3>
__global__ __launch_bounds__(256) void k_gemm(const u16* __restrict__ Ah, const u16* __restrict__ Al,
                                              const u16* __restrict__ Bh, const u16* __restrict__ Bl,
                                              const u16* __restrict__ Btl,
                                              const float* __restrict__ biasm, const float* __restrict__ biasl,
                                              void* __restrict__ Out, int Kc, int Ktot, int N,
                                              const int* __restrict__ cnt) {
    __shared__ u16 sA[128 * 64];
    __shared__ u16 sB[128 * 64];
    int tid = threadIdx.x, lane = tid & 63, wave = tid >> 6;
    int bn = blockIdx.x, t = blockIdx.y, kc = blockIdx.z;
    int tile = t, storeLo, storeHi;
    const u16* Ap = Ah;
    const u16* Bp = Bh;
    const float* bias = biasm;
    if constexpr (DUAL) {
        int n0 = cnt[0];
        int tb = n0 >> 7;
        bool isMath = (t <= tb) && (t < NB / 128);
        tile = isMath ? t : t - 1;
        int lo = tile * 128, hi = lo + 128;
        if (isMath) { storeLo = lo; storeHi = n0 < hi ? n0 : hi; }
        else        { storeLo = n0 > lo ? n0 : lo; storeHi = hi; }
        if (storeLo >= storeHi) return;   // block-uniform
        if (!isMath) { Bp = Btl; bias = biasl; }
    } else {
        storeLo = t * 128; storeHi = storeLo + 128;
    }
    long kOff = 0;
    if constexpr (R3) {
        Ap = (kc == 2) ? Al : Ah;
        Bp = (kc == 1) ? Bl : Bh;
    } else {
        kOff = (long)kc * Kc;
    }
    f32x4 acc[4][4];
#pragma unroll
    for (int i = 0; i < 4; i++)
#pragma unroll
        for (int j = 0; j < 4; j++) acc[i][j] = (f32x4)0.f;
    int wm = (wave & 1) * 64, wn = (wave >> 1) * 64;
    const long ks = (long)Ktot * 2;
    const char* aBase = (const char*)Ap + ((size_t)tile * 128 * Ktot + kOff) * 2;
    const char* bBase = (const char*)Bp + ((size_t)bn * 128 * Ktot + kOff) * 2;
    for (int k0 = 0; k0 < Kc; k0 += 64) {
        stage_tile(aBase + (long)k0 * 2, ks, sA, tid);
        stage_tile(bBase + (long)k0 * 2, ks, sB, tid);
        __syncthreads();
#pragma unroll
        for (int kk = 0; kk < 2; kk++) {
            int kofs = kk * 64 + (lane >> 4) * 16;
            bf16x8 vb[4];
#pragma unroll
            for (int ni = 0; ni < 4; ni++)
                vb[ni] = *(const bf16x8*)((const char*)sB + (wn + ni * 16 + (lane & 15)) * 128 + kofs);
#pragma unroll
            for (int mi = 0; mi < 4; mi++) {
                bf16x8 va = *(const bf16x8*)((const char*)sA + (wm + mi * 16 + (lane & 15)) * 128 + kofs);
#pragma unroll
                for (int ni = 0; ni < 4; ni++)
                    acc[mi][ni] = __builtin_amdgcn_mfma_f32_16x16x32_bf16(va, vb[ni], acc[mi][ni], 0, 0, 0);
            }
        }
        __syncthreads();
    }
    int quad = lane >> 4, cl = lane & 15;
#pragma unroll
    for (int mi = 0; mi < 4; mi++)
#pragma unroll
        for (int r = 0; r < 4; r++) {
            int grow = tile * 128 + wm + mi * 16 + quad * 4 + r;
            if (grow < storeLo || grow >= storeHi) continue;
#pragma unroll
            for (int ni = 0; ni < 4; ni++) {
                int col = bn * 128 + wn + ni * 16 + cl;
                if constexpr (EPI == 0) {
                    float v = acc[mi][ni][r] + bias[col];
                    ((u16*)Out)[(size_t)grow * N + col] = f2b(fmaxf(v, 0.f));
                } else {
                    ((float*)Out)[((size_t)kc * NB + grow) * N + col] = acc[mi][ni][r];
                }
            }
        }
}

// ---------------- router heads: sum 3 partials + bias + relu, fp32 dots, argmaxes, compaction ----------------
__global__ __launch_bounds__(256) void k_heads(const float* __restrict__ P,   // [3][NB][HRD]
                                               const float* __restrict__ br,
                                               const float* __restrict__ Wd, const float* __restrict__ bd,
                                               const float* __restrict__ Wm, const float* __restrict__ Wl,
                                               int* __restrict__ cnt, int* __restrict__ perm,
                                               float* __restrict__ wsc, int* __restrict__ eic) {
    const size_t CH = (size_t)NB * HRD;
    int lane = threadIdx.x & 63, wave = threadIdx.x >> 6;
    int r = blockIdx.x * 4 + wave;
    const float4* p0 = (const float4*)(P + (size_t)r * HRD);
    const float4* p1 = (const float4*)(P + CH + (size_t)r * HRD);
    const float4* p2 = (const float4*)(P + 2 * CH + (size_t)r * HRD);
    const float4* b4 = (const float4*)br;
    float hv[8];
#pragma unroll
    for (int j2 = 0; j2 < 2; j2++) {
        float4 a0 = p0[lane * 2 + j2], a1 = p1[lane * 2 + j2], a2 = p2[lane * 2 + j2];
        float4 bb = b4[lane * 2 + j2];
        hv[j2 * 4 + 0] = fmaxf(a0.x + a1.x + a2.x + bb.x, 0.f);
        hv[j2 * 4 + 1] = fmaxf(a0.y + a1.y + a2.y + bb.y, 0.f);
        hv[j2 * 4 + 2] = fmaxf(a0.z + a1.z + a2.z + bb.z, 0.f);
        hv[j2 * 4 + 3] = fmaxf(a0.w + a1.w + a2.w + bb.w, 0.f);
    }
    float a[10];
#pragma unroll
    for (int t = 0; t < 10; t++) a[t] = 0.f;
    int kbase = lane * 8;
#pragma unroll
    for (int j = 0; j < 8; j++) {
        int k = kbase + j;
        float h_ = hv[j];
        float2 wd = ((const float2*)Wd)[k];
        a[0] += h_ * wd.x; a[1] += h_ * wd.y;
        float4 wm = ((const float4*)Wm)[k];
        a[2] += h_ * wm.x; a[3] += h_ * wm.y; a[4] += h_ * wm.z; a[5] += h_ * wm.w;
        float4 wl = ((const float4*)Wl)[k];
        a[6] += h_ * wl.x; a[7] += h_ * wl.y; a[8] += h_ * wl.z; a[9] += h_ * wl.w;
    }
#pragma unroll
    for (int t = 0; t < 10; t++)
#pragma unroll
        for (int off = 32; off > 0; off >>= 1) a[t] += __shfl_down(a[t], off);
    if (lane == 0) {
        float d0 = a[0] + bd[0], d1 = a[1] + bd[1];
        int primary = (d1 > d0) ? 1 : 0;                       // first-max tie-break
        float w = 1.f / (1.f + expf(-fabsf(d0 - d1)));         // softmax weight of chosen
        int mi = 0; float mv = a[2];
        if (a[3] > mv) { mv = a[3]; mi = 1; }
        if (a[4] > mv) { mv = a[4]; mi = 2; }
        if (a[5] > mv) { mv = a[5]; mi = 3; }
        int li = 0; float lv = a[6];
        if (a[7] > lv) { lv = a[7]; li = 1; }
        if (a[8] > lv) { lv = a[8]; li = 2; }
        if (a[9] > lv) { lv = a[9]; li = 3; }
        int pos;
        if (primary == 0) pos = atomicAdd(&cnt[0], 1);
        else              pos = NB - 1 - atomicAdd(&cnt[1], 1);
        perm[pos] = r; wsc[pos] = w; eic[pos] = (primary == 0) ? mi : li;
    }
}

// ---------------- gather: xin_c[i] = bf16(x[perm[i]] + emb[eic[i]]) ----------------
__global__ __launch_bounds__(256) void k_gather(const float* __restrict__ x,
                                                const float* __restrict__ op_emb,
                                                const float* __restrict__ task_emb,
                                                const int* __restrict__ perm, const int* __restrict__ eic,
                                                const int* __restrict__ cnt, u16* __restrict__ xin) {
    int lane = threadIdx.x & 63, wave = threadIdx.x >> 6;
    int i = blockIdx.x * 4 + wave;
    int n0 = cnt[0];
    int r = perm[i];
    const float* emb = ((i >= n0) ? task_emb : op_emb) + (size_t)eic[i] * DD;
    const float4* x4 = (const float4*)(x + (size_t)r * DD);
    const float4* e4 = (const float4*)emb;
    ushort4* o4 = (ushort4*)(xin + (size_t)i * DD);
#pragma unroll
    for (int j = 0; j < 4; j++) {
        int idx = lane + j * 64;
        float4 xv = x4[idx], ev = e4[idx];
        ushort4 o;
        o.x = f2b(xv.x + ev.x); o.y = f2b(xv.y + ev.y);
        o.z = f2b(xv.z + ev.z); o.w = f2b(xv.w + ev.w);
        o4[idx] = o;
    }
}

// ---------------- L2 epilogue: fused = bf16((p0+p1+bias_sel) * wsel), per compacted row ----------------
__global__ __launch_bounds__(256) void k_epi_l2(const float* __restrict__ P,   // [2][NB][DD]
                                                const float* __restrict__ bm, const float* __restrict__ bl,
                                                const float* __restrict__ wsc, const int* __restrict__ cnt,
                                                ushort4* __restrict__ fused) {
    const size_t CH = (size_t)NB * DD;
    int i4 = blockIdx.x * 256 + threadIdx.x;
    int row = i4 >> 8, c4 = i4 & 255;
    int n0 = cnt[0];
    float w = wsc[row];
    const float4* bias = (const float4*)((row < n0) ? bm : bl);
    float4 p0 = ((const float4*)P)[i4];
    float4 p1 = ((const float4*)(P + CH))[i4];
    float4 bb = bias[c4];
    ushort4 o;
    o.x = f2b((p0.x + p1.x + bb.x) * w);
    o.y = f2b((p0.y + p1.y + bb.y) * w);
    o.z = f2b((p0.z + p1.z + bb.z) * w);
    o.w = f2b((p0.w + p1.w + bb.w) * w);
    fused[i4] = o;
}

// ---------------- F2 epilogue: d_out[perm[row]] = p0+p1+b_f2 + resid(bf16) ----------------
__global__ __launch_bounds__(256) void k_epi_f2(const float* __restrict__ P,   // [2][NB][DD]
                                                const float* __restrict__ bf,
                                                const ushort4* __restrict__ resid,
                                                const int* __restrict__ perm,
                                                float4* __restrict__ out) {
    const size_t CH = (size_t)NB * DD;
    int i4 = blockIdx.x * 256 + threadIdx.x;
    int row = i4 >> 8, c4 = i4 & 255;
    float4 p0 = ((const float4*)P)[i4];
    float4 p1 = ((const float4*)(P + CH))[i4];
    float4 bb = ((const float4*)bf)[c4];
    ushort4 rs = resid[i4];
    float4 o;
    o.x = p0.x + p1.x + bb.x + b2f(rs.x);
    o.y = p0.y + p1.y + bb.y + b2f(rs.y);
    o.z = p0.z + p1.z + bb.z + b2f(rs.z);
    o.w = p0.w + p1.w + bb.w + b2f(rs.w);
    out[(size_t)perm[row] * 256 + c4] = o;
}

extern "C" void kernel_launch(void* const* d_in, const int* in_sizes, int n_in,
                              void* d_out, int out_size, void* d_ws, size_t ws_size,
                              hipStream_t stream) {
    const float* x      = (const float*)d_in[0];
    const float* W_r1   = (const float*)d_in[1];
    const float* b_r1   = (const float*)d_in[2];
    const float* W_dom  = (const float*)d_in[3];
    const float* b_dom  = (const float*)d_in[4];
    const float* W_mop  = (const float*)d_in[5];
    const float* W_lt   = (const float*)d_in[6];
    const float* op_emb = (const float*)d_in[7];
    const float* W_m1   = (const float*)d_in[8];
    const float* b_m1   = (const float*)d_in[9];
    const float* W_m2   = (const float*)d_in[10];
    const float* b_m2   = (const float*)d_in[11];
    const float* task_emb = (const float*)d_in[12];
    const float* W_l1   = (const float*)d_in[13];
    const float* b_l1   = (const float*)d_in[14];
    const float* W_l2   = (const float*)d_in[15];
    const float* b_l2   = (const float*)d_in[16];
    const float* W_f1   = (const float*)d_in[17];
    const float* b_f1   = (const float*)d_in[18];
    const float* W_f2   = (const float*)d_in[19];
    const float* b_f2   = (const float*)d_in[20];

    char* wsp = (char*)d_ws;
    size_t off = 0;
    auto take = [&](size_t bytes) -> char* {
        char* p = wsp + off;
        off += (bytes + 255) & ~(size_t)255;
        return p;
    };
    u16* Wr_hi = (u16*)take((size_t)HRD * DD * 2);   // 1 MB
    u16* Wr_lo = (u16*)take((size_t)HRD * DD * 2);   // 1 MB
    u16* Wm1t  = (u16*)take((size_t)HED * DD * 2);   // 8 MB
    u16* Wl1t  = (u16*)take((size_t)HED * DD * 2);   // 8 MB
    u16* Wm2t  = (u16*)take((size_t)DD * HED * 2);   // 8 MB
    u16* Wl2t  = (u16*)take((size_t)DD * HED * 2);   // 8 MB
    u16* Wf1t  = (u16*)take((size_t)HFD * DD * 2);   // 4 MB
    u16* Wf2t  = (u16*)take((size_t)DD * HFD * 2);   // 4 MB
    u16* hid   = (u16*)take((size_t)NB * HED * 2);   // 64 MB
    float* pool = (float*)take((size_t)2 * NB * DD * 4);  // 64 MB: x_hi/x_lo then L2 partials
    u16* xin   = (u16*)take((size_t)NB * DD * 2);    // 16 MB
    u16* fused = (u16*)take((size_t)NB * DD * 2);    // 16 MB
    int* cnt   = (int*)take(256);
    int* perm  = (int*)take(NB * 4);
    int* eic   = (int*)take(NB * 4);
    float* wsc = (float*)take(NB * 4);
    // lifetime-disjoint aliases:
    u16* x_hi    = (u16*)pool;                         // [split -> router]
    u16* x_lo    = (u16*)pool + (size_t)NB * DD;
    float* Hpart = (float*)hid;                        // [3][NB][HRD] fp32 = 48 MB, router->heads (before L1 writes hid)
    float* L2part = pool;                              // [2][NB][DD] fp32 = 64 MB, L2->epi (x_hi/lo dead)
    u16* hid2    = Wm1t;                               // F1 out 32 MB over Wm1t..Wl2t (dead after L2)
    float* F2part = (float*)hid;                       // [2][NB][DD] fp32 = 64 MB, F2->epi (hid dead after L2)

    k_init<<<1, 64, 0, stream>>>(cnt);
    k_split<<<(NB * DD / 4) / 256, 256, 0, stream>>>((const float4*)x, (ushort4*)x_hi, (ushort4*)x_lo);
    k_transpose_split<<<dim3(HRD / 64, DD / 64), 256, 0, stream>>>(W_r1, Wr_hi, Wr_lo, DD, HRD);
    k_transpose<<<dim3(HED / 64, DD / 64), 256, 0, stream>>>(W_m1, Wm1t, DD, HED);
    k_transpose<<<dim3(HED / 64, DD / 64), 256, 0, stream>>>(W_l1, Wl1t, DD, HED);
    k_transpose<<<dim3(DD / 64, HED / 64), 256, 0, stream>>>(W_m2, Wm2t, HED, DD);
    k_transpose<<<dim3(DD / 64, HED / 64), 256, 0, stream>>>(W_l2, Wl2t, HED, DD);
    k_transpose<<<dim3(HFD / 64, DD / 64), 256, 0, stream>>>(W_f1, Wf1t, DD, HFD);
    k_transpose<<<dim3(DD / 64, HFD / 64), 256, 0, stream>>>(W_f2, Wf2t, HFD, DD);

    // router GEMM: 3-way split-K (xh*Wh, xh*Wl, xl*Wh) -> fp32 partials
    k_gemm<4, false, true><<<dim3(HRD / 128, NB / 128, 3), 256, 0, stream>>>(
        x_hi, x_lo, Wr_hi, Wr_lo, nullptr, nullptr, nullptr, Hpart, DD, DD, HRD, nullptr);
    k_heads<<<NB / 4, 256, 0, stream>>>(Hpart, b_r1, W_dom, b_dom, W_mop, W_lt, cnt, perm, wsc, eic);
    k_gather<<<NB / 4, 256, 0, stream>>>(x, op_emb, task_emb, perm, eic, cnt, xin);

    // expert layer 1 fused (relu -> hid), K=1024 single chunk, direct epilogue
    k_gemm<0, true, false><<<dim3(HED / 128, NB / 128 + 1, 1), 256, 0, stream>>>(
        xin, nullptr, Wm1t, nullptr, Wl1t, b_m1, b_l1, hid, DD, DD, HED, cnt);
    // expert layer 2 fused: split-K=2 (Kc=2048) -> fp32 partials, then epilogue scales by wsel
    k_gemm<4, true, false><<<dim3(DD / 128, NB / 128 + 1, 2), 256, 0, stream>>>(
        hid, nullptr, Wm2t, nullptr, Wl2t, nullptr, nullptr, L2part, HED / 2, HED, DD, cnt);
    k_epi_l2<<<(NB * DD / 4) / 256, 256, 0, stream>>>(L2part, b_m2, b_l2, wsc, cnt, (ushort4*)fused);
    // fusion MLP
    k_gemm<0, false, false><<<dim3(HFD / 128, NB / 128, 1), 256, 0, stream>>>(
        fused, nullptr, Wf1t, nullptr, nullptr, b_f1, nullptr, hid2, DD, DD, HFD, nullptr);
    k_gemm<4, false, false><<<dim3(DD / 128, NB / 128, 2), 256, 0, stream>>>(
        hid2, nullptr, Wf2t, nullptr, nullptr, nullptr, nullptr, F2part, HFD / 2, HFD, DD, nullptr);
    k_epi_f2<<<(NB * DD / 4) / 256, 256, 0, stream>>>(F2part, b_f2, (const ushort4*)fused, perm, (float4*)d_out);
}